// Round 5
// baseline (123.208 us; speedup 1.0000x reference)
//
#include <hip/hip_runtime.h>
#include <hip/hip_bf16.h>
#include <cstdint>
#include <cstddef>

#define N_SONGS 100000
#define EMBED   64
#define BATCH   1024
#define SEQL    200
#define NTILES  782          // ceil(100000/128)
#define GBLOCKS (NTILES * 8) // 6256 = 8 XCDs * 782 exactly

typedef __attribute__((ext_vector_type(8)))  __bf16 bf16x8;
typedef __attribute__((ext_vector_type(16))) float  f32x16;
typedef __attribute__((ext_vector_type(4)))  float  f32x4;

__device__ __forceinline__ unsigned short f2b_rne(float x) {
    union { float f; uint32_t u; } v; v.f = x;
    uint32_t u = v.u;
    return (unsigned short)((u + 0x7FFFu + ((u >> 16) & 1u)) >> 16);
}

// ---- Kernel 1: masked-mean pooling -> bf16 (one block per sample) ----
__global__ __launch_bounds__(256) void pool_kernel(const int* __restrict__ songs,
                                                   const float* __restrict__ emb,
                                                   unsigned short* __restrict__ pooled) {
    __shared__ float part[4][EMBED];
    __shared__ int   cnts[4];

    int b = blockIdx.x;
    int t = threadIdx.x;
    int d = t & 63;        // embed dim
    int c = t >> 6;        // L-chunk 0..3

    const int* row = songs + (size_t)b * SEQL;
    float acc = 0.f;
    int cnt = 0;
    int l0 = c * (SEQL / 4);
    for (int l = l0; l < l0 + SEQL / 4; ++l) {
        int id = row[l];                    // wave-uniform
        if (id != N_SONGS) {
            acc += emb[(size_t)id * EMBED + d];
            ++cnt;
        }
    }
    part[c][d] = acc;
    if (d == 0) cnts[c] = cnt;
    __syncthreads();
    if (t < EMBED) {
        float s = part[0][t] + part[1][t] + part[2][t] + part[3][t];
        float n = (float)(cnts[0] + cnts[1] + cnts[2] + cnts[3]);  // >= 1 always
        pooled[(size_t)b * EMBED + t] = f2b_rne(s / n);
    }
}

// ---- Kernel 2: out[1024 x 100000] = sigmoid(pooled @ W^T + b), 32x32x16 MFMA ----
// W is read as fp32 and converted to bf16 in-register (RNE) — no separate wconv pass.
// XCD-aware remap: idx = (bid%8)*NTILES + bid/8; nt = idx>>3, mt = idx&7. Each XCD
// owns a contiguous ~98-nt band (W slice ~3.1MB fp32 -> L2-resident) and iterates
// mt fastest so the same W slice is hot across all 8 m-tiles.
// D layout: col = lane&31, row = (r&3)+8*(r>>2)+4*(lane>>5) -> each store instr covers
// two 128B-aligned full lines; NT stores keep the 400MB stream out of L2.
__global__ __launch_bounds__(256, 2) void gemm_kernel(const unsigned short* __restrict__ pooled,
                                                      const float* __restrict__ W,
                                                      const float* __restrict__ bias,
                                                      float* __restrict__ out) {
    int idx = (blockIdx.x & 7) * NTILES + (blockIdx.x >> 3);
    int nt = idx >> 3, mt = idx & 7;

    int t = threadIdx.x;
    int w = t >> 6, lane = t & 63;
    int wm = w >> 1, wn = w & 1;
    int lc = lane & 31;      // row (A) / col (B,D) within 32
    int hi = lane >> 5;      // k-half selector

    int m0 = mt * 128 + wm * 64;
    int n0 = nt * 128 + wn * 64;

    // A fragments: pooled[m][k] (bf16, tiny, L2-resident)
    bf16x8 afrag[4][2];
#pragma unroll
    for (int ks = 0; ks < 4; ++ks)
#pragma unroll
        for (int mi = 0; mi < 2; ++mi) {
            const unsigned short* p =
                pooled + (size_t)(m0 + mi * 32 + lc) * EMBED + ks * 16 + hi * 8;
            afrag[ks][mi] = *(const bf16x8*)p;
        }

    // B fragments: B[k][n] = W[n][k], fp32 -> bf16 in-register
    bf16x8 bfrag[4][2];
#pragma unroll
    for (int ks = 0; ks < 4; ++ks)
#pragma unroll
        for (int nj = 0; nj < 2; ++nj) {
            int n = n0 + nj * 32 + lc;
            n = n < N_SONGS ? n : N_SONGS - 1;   // clamp; store is guarded
            const float* p = W + (size_t)n * EMBED + ks * 16 + hi * 8;
            f32x4 v0 = *(const f32x4*)p;
            f32x4 v1 = *(const f32x4*)(p + 4);
            bf16x8 r;
#pragma unroll
            for (int e = 0; e < 4; ++e) { r[e] = (__bf16)v0[e]; r[e + 4] = (__bf16)v1[e]; }
            bfrag[ks][nj] = r;
        }

    f32x16 acc[2][2];
#pragma unroll
    for (int mi = 0; mi < 2; ++mi)
#pragma unroll
        for (int nj = 0; nj < 2; ++nj)
#pragma unroll
            for (int r = 0; r < 16; ++r)
                acc[mi][nj][r] = 0.f;

#pragma unroll
    for (int ks = 0; ks < 4; ++ks)
#pragma unroll
        for (int mi = 0; mi < 2; ++mi)
#pragma unroll
            for (int nj = 0; nj < 2; ++nj)
                acc[mi][nj] = __builtin_amdgcn_mfma_f32_32x32x16_bf16(
                    afrag[ks][mi], bfrag[ks][nj], acc[mi][nj], 0, 0, 0);

    // Epilogue: +bias, sigmoid, non-temporal store
#pragma unroll
    for (int nj = 0; nj < 2; ++nj) {
        int n = n0 + nj * 32 + lc;
        if (n >= N_SONGS) continue;
        float bv = bias[n];
#pragma unroll
        for (int mi = 0; mi < 2; ++mi) {
#pragma unroll
            for (int r = 0; r < 16; ++r) {
                int row = m0 + mi * 32 + (r & 3) + 8 * (r >> 2) + 4 * hi;
                float x = acc[mi][nj][r] + bv;
                float e = __expf(-x);
                float s = __builtin_amdgcn_rcpf(1.0f + e);
                __builtin_nontemporal_store(s, &out[(size_t)row * N_SONGS + n]);
            }
        }
    }
}

extern "C" void kernel_launch(void* const* d_in, const int* in_sizes, int n_in,
                              void* d_out, int out_size, void* d_ws, size_t ws_size,
                              hipStream_t stream) {
    const int*   songs = (const int*)d_in[0];
    const float* emb   = (const float*)d_in[1];
    const float* W     = (const float*)d_in[2];
    const float* bias  = (const float*)d_in[3];
    float* out = (float*)d_out;

    unsigned short* pooled = (unsigned short*)d_ws;   // 128 KB

    hipLaunchKernelGGL(pool_kernel, dim3(BATCH), dim3(256), 0, stream,
                       songs, emb, pooled);
    hipLaunchKernelGGL(gemm_kernel, dim3(GBLOCKS), dim3(256), 0, stream,
                       pooled, W, bias, out);
}